// Round 4
// baseline (83.325 us; speedup 1.0000x reference)
//
#include <hip/hip_runtime.h>

typedef unsigned long long u64;
typedef unsigned short u16;

#define HH 384
#define WW 384
#define BB 8
#define CC 3
#define NMASK (BB*CC)        // 24
#define PLANE (HH*WW)        // 147456
#define NW 6                 // 384 rows = 6 x 64-bit words
#define ROWS_PG 8            // 8 | 64 -> a row group never spans bitmask words
#define GROUPS 48            // 384/8 -> 384 blocks (was 768: ~20ns/WG dispatch tax)
#define CHUNK 4              // fallback ring radii per batch
#define INF_F 1.0e6f

// ---------------------------------------------------------------------------
// Algebra: only the 3 per-class bg EDT fields d_c(q)=dist(q,{t==c}) are
// computed. fg_c(q)=dist(q,{t!=c}) = 0 where t(q)!=c, else min of the other
// two d's (dist-to-union = min of dists; bit-exact, sqrt monotone).
// loss = sum_m S_bg/max_bg - S_fg/max_fg  (divide-after-sum; ~1e-7 rel)
// mask non-empty <=> max_bg <= 1000 (real EDT max < 542; empty-set >= 1e6)
//
// Structure: 3 kernels, stream-ordered. Fused last-block variants measured
// SLOWER (r1 +15us fences, r2 +10us agent-RMW serialization). Keep separate.
//
// Round-4 theory (from r2/r3 block-count regression): wall cost ~20ns per
// workgroup (dispatch ramp; explains Occ 32% < 56% resident and why all
// throughput estimates were 4-5x optimistic). Fix: halve WG count at
// constant work.
//  * edt4w ROWS_PG 4->8: 384 blocks. The 8-row group still lives in ONE
//    64-bit bitmask word (8|64), so the bm front (18 loads + P/N scans +
//    word[c]) is loaded/computed ONCE for 8 rows (was per 4).
//  * buildbm: 768-thread blocks, grid (8,6,2) = 96 blocks (was 192).
//  * fallback marked __builtin_expect cold -> compiler sinks the x24
//    unrolled dead blob out of the hot I$ stream.
//
// ws layout:
//   u64   bm[BB][CC][NW][WW]        column seed bitmasks (442368 B)
//   float out12[NMASK][4][GROUPS]   per-(b,c): {Sbg,Sfg,Mbg,Mfg} x rowgroup
// ---------------------------------------------------------------------------

template <int CTRL>
__device__ __forceinline__ float dpp_mov(float v) {
    return __int_as_float(__builtin_amdgcn_update_dpp(
        0, __float_as_int(v), CTRL, 0xf, 0xf, true));
}
__device__ __forceinline__ float wave_sum64(float v) {
    v += dpp_mov<0x111>(v);   // row_shr:1
    v += dpp_mov<0x112>(v);   // row_shr:2
    v += dpp_mov<0x114>(v);   // row_shr:4
    v += dpp_mov<0x118>(v);   // row_shr:8  -> lane15 of each row = row sum
    v += dpp_mov<0x142>(v);   // row_bcast:15
    v += dpp_mov<0x143>(v);   // row_bcast:31 -> lane63 = total
    return v;                 // valid in lane 63 (identity 0 shifts in zeros)
}
__device__ __forceinline__ float wave_max64(float v) {
    v = fmaxf(v, dpp_mov<0x111>(v));
    v = fmaxf(v, dpp_mov<0x112>(v));
    v = fmaxf(v, dpp_mov<0x114>(v));
    v = fmaxf(v, dpp_mov<0x118>(v));
    v = fmaxf(v, dpp_mov<0x142>(v));
    v = fmaxf(v, dpp_mov<0x143>(v));
    return v;                 // valid in lane 63 (identity 0: inputs >= 0)
}

// Grid (BB, NW, 2), 768 threads: thread (q2,j) builds a 16-bit partial of the
// 64-row bitmask word for its column, all 3 classes (u16 stores, no atomics).
__global__ __launch_bounds__(768) void buildbm(const int* __restrict__ targets,
                                               u16* __restrict__ bm16) {
    int b = blockIdx.x, w = blockIdx.y;
    int q = blockIdx.z * 2 + threadIdx.x / WW;
    int j = threadIdx.x % WW;
    const int* tg = targets + (size_t)b * PLANE + (w * 64 + q * 16) * WW + j;
    int t[16];
#pragma unroll
    for (int r = 0; r < 16; ++r) t[r] = tg[r * WW];   // batch: one stall group
    unsigned m0 = 0, m1 = 0, m2 = 0;
#pragma unroll
    for (int r = 0; r < 16; ++r) {
        unsigned bit = 1u << r;
        m0 |= (t[r] == 0) ? bit : 0u;
        m1 |= (t[r] == 1) ? bit : 0u;
        m2 |= (t[r] == 2) ? bit : 0u;
    }
    size_t base = (((size_t)b * CC) * NW + w) * WW + j;          // c = 0
    bm16[base * 4 + q] = (u16)m0;
    bm16[(base + (size_t)NW * WW) * 4 + q] = (u16)m1;
    bm16[(base + 2 * (size_t)NW * WW) * 4 + q] = (u16)m2;
}

// Grid (GROUPS, BB): block = 8 rows x 384 cols, all 3 classes.
__global__ __launch_bounds__(WW, 3) void edt4w(const u64* __restrict__ bm,
                                               const float* __restrict__ logits,
                                               float* __restrict__ out12) {
    __shared__ __align__(16) float g2s[ROWS_PG][CC][WW];   // 36864 B
    __shared__ float red[12][WW / 64];
    int g = blockIdx.x, b = blockIdx.y;
    int j = threadIdx.x;
    int i0 = g * ROWS_PG;
    int w = i0 >> 6;
    int wbase = w << 6;

    // ---- batch-issue ALL global loads: one stall group per wave ----
    u64 wb[CC][NW];
#pragma unroll
    for (int c = 0; c < CC; ++c)
#pragma unroll
        for (int wq = 0; wq < NW; ++wq)
            wb[c][wq] = bm[(((size_t)b * CC + c) * NW + wq) * WW + j];

    const float* lg = logits + ((size_t)b * CC * HH + i0) * WW + j;
    float lv[ROWS_PG][CC];
#pragma unroll
    for (int rl = 0; rl < ROWS_PG; ++rl) {
        lv[rl][0] = lg[rl * WW];
        lv[rl][1] = lg[PLANE + rl * WW];
        lv[rl][2] = lg[2 * PLANE + rl * WW];
    }

    u64 word[CC];
    int P[CC], N[CC];
#pragma unroll
    for (int c = 0; c < CC; ++c) {
        int p = -1, n = -1;
#pragma unroll
        for (int wq = 0; wq < NW; ++wq)
            if (wq < w && wb[c][wq]) p = wq * 64 + 63 - __builtin_clzll(wb[c][wq] | 1ull);
#pragma unroll
        for (int wq = NW - 1; wq >= 0; --wq)
            if (wq > w && wb[c][wq]) n = wq * 64 + (int)__builtin_ctzll(wb[c][wq] | 0x8000000000000000ull);
        P[c] = p; N[c] = n;
        // dynamic-uniform index w: select chain, not scratch (rule #20)
        u64 wd = wb[c][0];
#pragma unroll
        for (int wq = 1; wq < NW; ++wq) wd = (w == wq) ? wb[c][wq] : wd;
        word[c] = wd;
    }

    // Phase A: 8 rows x 3 classes of exact column distances -> LDS.
    u64 lowmask = ((1ull << (i0 & 63)) << 1) - 1ull;    // bits 0..bi
#pragma unroll
    for (int rl = 0; rl < ROWS_PG; ++rl) {
        int i = i0 + rl;
        u64 himask = ~(lowmask >> 1);                   // bits bi..63
#pragma unroll
        for (int c = 0; c < CC; ++c) {
            u64 lo = word[c] & lowmask;
            int last = lo ? (wbase + 63 - __builtin_clzll(lo | 1ull)) : P[c];
            u64 hi = word[c] & himask;
            int next = hi ? (wbase + (int)__builtin_ctzll(hi | 0x8000000000000000ull)) : N[c];
            float fwd = (last >= 0) ? (float)(i - last) : (INF_F + (float)(i + 1));
            float bwd = (next >= 0) ? (float)(next - i) : (INF_F + (float)(HH - i));
            float gc = fminf(fwd, bwd);
            g2s[rl][c][j] = gc * gc;
        }
        lowmask = (lowmask << 1) | 1ull;
    }
    __syncthreads();   // vmcnt(0) drain here also retires the lv prefetch

    // aligned 12-float window covering [j-4, j+4]
    int basek = (j - 4) & ~3;
    if (basek < 0) basek = 0;
    if (basek > WW - 12) basek = WW - 12;
    float df0 = (float)(basek - j);

    // Phase B: per row, softmax once + 3 window searches (+never-fires fallback).
    // Pure LDS+VALU: logits already in registers.
    float Sb0 = 0.f, Sb1 = 0.f, Sb2 = 0.f, Sf0 = 0.f, Sf1 = 0.f, Sf2 = 0.f;
    float Mb0 = 0.f, Mb1 = 0.f, Mb2 = 0.f, Mf0 = 0.f, Mf1 = 0.f, Mf2 = 0.f;
#pragma unroll
    for (int rl = 0; rl < ROWS_PG; ++rl) {
        int bi = (i0 + rl) & 63;
        float l0 = lv[rl][0], l1 = lv[rl][1], l2 = lv[rl][2];
        float mx = fmaxf(l0, fmaxf(l1, l2));
        float x0 = __expf(l0 - mx), x1 = __expf(l1 - mx), x2 = __expf(l2 - mx);
        float rs = __fdividef(1.0f, x0 + x1 + x2);
        float pr0 = x0 * rs, pr1 = x1 * rs, pr2 = x2 * rs;

        float d[CC];
#pragma unroll
        for (int c = 0; c < CC; ++c) {
            const float* g2 = g2s[rl][c];
            // 3 independent b128 loads — one latency wait, no chain
            float4 W0 = *(const float4*)(g2 + basek);
            float4 W1 = *(const float4*)(g2 + basek + 4);
            float4 W2 = *(const float4*)(g2 + basek + 8);
            float df = df0;
            float mn;
            mn =           fmaf(df, df, W0.x);  df += 1.f;
            mn = fminf(mn, fmaf(df, df, W0.y)); df += 1.f;
            mn = fminf(mn, fmaf(df, df, W0.z)); df += 1.f;
            mn = fminf(mn, fmaf(df, df, W0.w)); df += 1.f;
            mn = fminf(mn, fmaf(df, df, W1.x)); df += 1.f;
            mn = fminf(mn, fmaf(df, df, W1.y)); df += 1.f;
            mn = fminf(mn, fmaf(df, df, W1.z)); df += 1.f;
            mn = fminf(mn, fmaf(df, df, W1.w)); df += 1.f;
            mn = fminf(mn, fmaf(df, df, W2.x)); df += 1.f;
            mn = fminf(mn, fmaf(df, df, W2.y)); df += 1.f;
            mn = fminf(mn, fmaf(df, df, W2.z)); df += 1.f;
            mn = fminf(mn, fmaf(df, df, W2.w));
            if (__builtin_expect(mn > 25.f, 0)) {   // radius-4 prune failed (P ~ 0)
                for (int r0 = 5; r0 < WW; r0 += CHUNK) {
                    float r0sq = (float)(r0 * r0);   // exact fp32 integer
                    if (r0sq >= mn) break;
                    float cl[CHUNK], cr[CHUNK];
#pragma unroll
                    for (int u = 0; u < CHUNK; ++u) {
                        int r = r0 + u;
                        int kl = j - r; kl = (kl < 0) ? 0 : kl;
                        int kr = j + r; kr = (kr > WW - 1) ? WW - 1 : kr;
                        cl[u] = g2[kl];
                        cr[u] = g2[kr];
                    }
#pragma unroll
                    for (int u = 0; u < CHUNK; ++u) {
                        float rr = (float)((r0 + u) * (r0 + u));
                        mn = fminf(mn, fminf(rr + cl[u], rr + cr[u]));
                    }
                }
            }
            d[c] = sqrtf(mn);
        }
        // fg_c = (t==c) ? min of other two bg dists : 0
        float f0 = ((word[0] >> bi) & 1ull) ? fminf(d[1], d[2]) : 0.f;
        float f1 = ((word[1] >> bi) & 1ull) ? fminf(d[0], d[2]) : 0.f;
        float f2 = ((word[2] >> bi) & 1ull) ? fminf(d[0], d[1]) : 0.f;

        Sb0 += pr0 * d[0]; Sb1 += pr1 * d[1]; Sb2 += pr2 * d[2];
        Sf0 += pr0 * f0;   Sf1 += pr1 * f1;   Sf2 += pr2 * f2;
        Mb0 = fmaxf(Mb0, d[0]); Mb1 = fmaxf(Mb1, d[1]); Mb2 = fmaxf(Mb2, d[2]);
        Mf0 = fmaxf(Mf0, f0);   Mf1 = fmaxf(Mf1, f1);   Mf2 = fmaxf(Mf2, f2);
    }

    // DPP wave reduction (VALU pipe) -> lane 63; then tiny cross-wave combine.
    float acc[12] = {Sb0, Sf0, Mb0, Mf0, Sb1, Sf1, Mb1, Mf1, Sb2, Sf2, Mb2, Mf2};
    int lane = j & 63, wid = j >> 6;
#pragma unroll
    for (int a = 0; a < 12; ++a) {
        bool ismax = (a & 2) != 0;         // k = a&3: 0,1 sums; 2,3 maxes
        float v = ismax ? wave_max64(acc[a]) : wave_sum64(acc[a]);
        if (lane == 63) red[a][wid] = v;
    }
    __syncthreads();
    if (j < 12) {
        int c = j >> 2, k = j & 3;
        bool ismax = (k & 2) != 0;
        float v = red[j][0];
#pragma unroll
        for (int t = 1; t < WW / 64; ++t)
            v = ismax ? fmaxf(v, red[j][t]) : (v + red[j][t]);
        out12[((size_t)(b * CC + c) * 4 + k) * GROUPS + g] = v;
    }
}

// One block: reduce 24 masks x 4 stats x 48 groups -> scalar loss.
__global__ __launch_bounds__(WW) void final_k(const float* __restrict__ out12,
                                              float* __restrict__ out) {
    __shared__ float contrib[NMASK];
    int t = threadIdx.x;
    int m = t >> 4, l = t & 15;            // 24 masks x 16 lanes
    const float* pm = out12 + (size_t)m * 4 * GROUPS;
    // batch all loads: one stall group instead of chained waits
    float t0[3], t1[3], t2[3], t3[3];
#pragma unroll
    for (int q = 0; q < 3; ++q) {
        int gg = q * 16 + l;
        t0[q] = pm[0 * GROUPS + gg];
        t1[q] = pm[1 * GROUPS + gg];
        t2[q] = pm[2 * GROUPS + gg];
        t3[q] = pm[3 * GROUPS + gg];
    }
    float sb = 0.f, sf = 0.f, mb = 0.f, mf = 0.f;
#pragma unroll
    for (int q = 0; q < 3; ++q) {
        sb += t0[q]; sf += t1[q];
        mb = fmaxf(mb, t2[q]); mf = fmaxf(mf, t3[q]);
    }
#pragma unroll
    for (int off = 8; off > 0; off >>= 1) {
        sb += __shfl_down(sb, off, 16);
        sf += __shfl_down(sf, off, 16);
        mb = fmaxf(mb, __shfl_down(mb, off, 16));
        mf = fmaxf(mf, __shfl_down(mf, off, 16));
    }
    if (l == 0) {
        float cv = 0.f;
        if (mb <= 1000.0f)                 // mask non-empty
            cv = sb / fmaxf(mb, 1e-12f) - sf / fmaxf(mf, 1e-12f);
        contrib[m] = cv;
    }
    __syncthreads();
    if (t == 0) {
        float tot = 0.f;
        for (int mk = 0; mk < NMASK; ++mk) tot += contrib[mk];
        out[0] = tot / (float)((size_t)BB * CC * PLANE);
    }
}

extern "C" void kernel_launch(void* const* d_in, const int* in_sizes, int n_in,
                              void* d_out, int out_size, void* d_ws, size_t ws_size,
                              hipStream_t stream) {
    const float* logits = (const float*)d_in[0];   // [8,3,384,384] f32
    const int* targets = (const int*)d_in[1];      // [8,384,384] i32
    float* out = (float*)d_out;                    // scalar f32

    u64* bm = (u64*)d_ws;                                       // 55296 u64
    float* out12 = (float*)(bm + (size_t)BB * CC * NW * WW);    // 4608 floats

    {
        dim3 grid(BB, NW, 2);                                   // 96 blocks
        buildbm<<<grid, 768, 0, stream>>>(targets, (u16*)bm);
    }
    {
        dim3 grid(GROUPS, BB);                                  // 48*8 = 384 blocks
        edt4w<<<grid, WW, 0, stream>>>(bm, logits, out12);
    }
    final_k<<<1, WW, 0, stream>>>(out12, out);
}

// Round 5
// 81.819 us; speedup vs baseline: 1.0184x; 1.0184x over previous
//
#include <hip/hip_runtime.h>

typedef unsigned long long u64;
typedef unsigned short u16;

#define HH 384
#define WW 384
#define BB 8
#define CC 3
#define NMASK (BB*CC)        // 24
#define PLANE (HH*WW)        // 147456
#define NW 6                 // 384 rows = 6 x 64-bit words
#define ROWS_PG 2            // 2 | 64 -> a row group never spans bitmask words
#define GROUPS 192           // 384/2 -> 1536 blocks = 6.0/CU exact balance
#define CHUNK 4              // fallback ring radii per batch
#define INF_F 1.0e6f

// ---------------------------------------------------------------------------
// Algebra: only the 3 per-class bg EDT fields d_c(q)=dist(q,{t==c}) are
// computed. fg_c(q)=dist(q,{t!=c}) = 0 where t(q)!=c, else min of the other
// two d's (dist-to-union = min of dists; bit-exact, sqrt monotone).
// loss = sum_m S_bg/max_bg - S_fg/max_fg  (divide-after-sum; ~1e-7 rel)
// mask non-empty <=> max_bg <= 1000 (real EDT max < 542; empty-set >= 1e6)
//
// Structure: 3 kernels, stream-ordered. Fused last-block variants measured
// SLOWER (r1 +15us fences, r2 +10us agent-RMW serialization). Keep separate.
//
// Cross-round ledger:
//  r0 ROWS_PG=4 768blk 3-kernel:        80.4
//  r1 fused+fences:                     99.8  (edt4w direct: 42-47us)
//  r2 fused relaxed, ROWS_PG=2:         90.0  (confounded: RMW backlog)
//  r3 3-kernel + batched loads:         79.0  (baseline)
//  r4 ROWS_PG=8 384blk:                 83.3  (1.5 blk/CU imbalance: +4.3
//     matches tax~0 model -> dispatch tax REFUTED as dominant)
//
// Round-5 experiment (single variable vs r3): ROWS_PG 4->2.
//  1536 blocks = 6.0/CU exact; ~4 resident blocks/CU (VGPR-capped via
//  __launch_bounds__(384,6) -> cap ~84, usage ~70, no spill) = ~24 waves/CU
//  vs r3's 18, with blocks at staggered phases -> uncorrelated stalls.
//  Tests the latency-hiding model (VALUBusy 20%, Occ 32%, HBM 2.5%:
//  edt4w is stall-bound, VALU floor ~5-8us of ~28us).
//
// ws layout:
//   u64   bm[BB][CC][NW][WW]        column seed bitmasks (442368 B)
//   float out12[NMASK][4][GROUPS]   per-(b,c): {Sbg,Sfg,Mbg,Mfg} x rowgroup
// ---------------------------------------------------------------------------

template <int CTRL>
__device__ __forceinline__ float dpp_mov(float v) {
    return __int_as_float(__builtin_amdgcn_update_dpp(
        0, __float_as_int(v), CTRL, 0xf, 0xf, true));
}
__device__ __forceinline__ float wave_sum64(float v) {
    v += dpp_mov<0x111>(v);   // row_shr:1
    v += dpp_mov<0x112>(v);   // row_shr:2
    v += dpp_mov<0x114>(v);   // row_shr:4
    v += dpp_mov<0x118>(v);   // row_shr:8  -> lane15 of each row = row sum
    v += dpp_mov<0x142>(v);   // row_bcast:15
    v += dpp_mov<0x143>(v);   // row_bcast:31 -> lane63 = total
    return v;                 // valid in lane 63 (identity 0 shifts in zeros)
}
__device__ __forceinline__ float wave_max64(float v) {
    v = fmaxf(v, dpp_mov<0x111>(v));
    v = fmaxf(v, dpp_mov<0x112>(v));
    v = fmaxf(v, dpp_mov<0x114>(v));
    v = fmaxf(v, dpp_mov<0x118>(v));
    v = fmaxf(v, dpp_mov<0x142>(v));
    v = fmaxf(v, dpp_mov<0x143>(v));
    return v;                 // valid in lane 63 (identity 0: inputs >= 0)
}

// Grid (BB, NW, 4): thread j builds a 16-bit partial of the 64-row bitmask
// word for its column, all 3 classes (u16 stores, little-endian, no atomics).
__global__ __launch_bounds__(WW) void buildbm(const int* __restrict__ targets,
                                              u16* __restrict__ bm16) {
    int b = blockIdx.x, w = blockIdx.y, q = blockIdx.z;
    int j = threadIdx.x;
    const int* tg = targets + (size_t)b * PLANE + (w * 64 + q * 16) * WW + j;
    int t[16];
#pragma unroll
    for (int r = 0; r < 16; ++r) t[r] = tg[r * WW];   // batch: one stall group
    unsigned m0 = 0, m1 = 0, m2 = 0;
#pragma unroll
    for (int r = 0; r < 16; ++r) {
        unsigned bit = 1u << r;
        m0 |= (t[r] == 0) ? bit : 0u;
        m1 |= (t[r] == 1) ? bit : 0u;
        m2 |= (t[r] == 2) ? bit : 0u;
    }
    size_t base = (((size_t)b * CC) * NW + w) * WW + j;          // c = 0
    bm16[base * 4 + q] = (u16)m0;
    bm16[(base + (size_t)NW * WW) * 4 + q] = (u16)m1;
    bm16[(base + 2 * (size_t)NW * WW) * 4 + q] = (u16)m2;
}

// Grid (GROUPS, BB): block = 2 rows x 384 cols, all 3 classes.
__global__ __launch_bounds__(WW, 6) void edt4w(const u64* __restrict__ bm,
                                               const float* __restrict__ logits,
                                               float* __restrict__ out12) {
    __shared__ __align__(16) float g2s[ROWS_PG][CC][WW];   // 9216 B
    __shared__ float red[12][WW / 64];
    int g = blockIdx.x, b = blockIdx.y;
    int j = threadIdx.x;
    int i0 = g * ROWS_PG;
    int w = i0 >> 6;
    int wbase = w << 6;

    // ---- batch-issue ALL global loads: one stall group per wave ----
    u64 wb[CC][NW];
#pragma unroll
    for (int c = 0; c < CC; ++c)
#pragma unroll
        for (int wq = 0; wq < NW; ++wq)
            wb[c][wq] = bm[(((size_t)b * CC + c) * NW + wq) * WW + j];

    const float* lg = logits + ((size_t)b * CC * HH + i0) * WW + j;
    float lv[ROWS_PG][CC];
#pragma unroll
    for (int rl = 0; rl < ROWS_PG; ++rl) {
        lv[rl][0] = lg[rl * WW];
        lv[rl][1] = lg[PLANE + rl * WW];
        lv[rl][2] = lg[2 * PLANE + rl * WW];
    }

    u64 word[CC];
    int P[CC], N[CC];
#pragma unroll
    for (int c = 0; c < CC; ++c) {
        int p = -1, n = -1;
#pragma unroll
        for (int wq = 0; wq < NW; ++wq)
            if (wq < w && wb[c][wq]) p = wq * 64 + 63 - __builtin_clzll(wb[c][wq] | 1ull);
#pragma unroll
        for (int wq = NW - 1; wq >= 0; --wq)
            if (wq > w && wb[c][wq]) n = wq * 64 + (int)__builtin_ctzll(wb[c][wq] | 0x8000000000000000ull);
        P[c] = p; N[c] = n;
        // dynamic-uniform index w: select chain, not scratch (rule #20)
        u64 wd = wb[c][0];
#pragma unroll
        for (int wq = 1; wq < NW; ++wq) wd = (w == wq) ? wb[c][wq] : wd;
        word[c] = wd;
    }

    // Phase A: 2 rows x 3 classes of exact column distances -> LDS.
    u64 lowmask = ((1ull << (i0 & 63)) << 1) - 1ull;    // bits 0..bi
#pragma unroll
    for (int rl = 0; rl < ROWS_PG; ++rl) {
        int i = i0 + rl;
        u64 himask = ~(lowmask >> 1);                   // bits bi..63
#pragma unroll
        for (int c = 0; c < CC; ++c) {
            u64 lo = word[c] & lowmask;
            int last = lo ? (wbase + 63 - __builtin_clzll(lo | 1ull)) : P[c];
            u64 hi = word[c] & himask;
            int next = hi ? (wbase + (int)__builtin_ctzll(hi | 0x8000000000000000ull)) : N[c];
            float fwd = (last >= 0) ? (float)(i - last) : (INF_F + (float)(i + 1));
            float bwd = (next >= 0) ? (float)(next - i) : (INF_F + (float)(HH - i));
            float gc = fminf(fwd, bwd);
            g2s[rl][c][j] = gc * gc;
        }
        lowmask = (lowmask << 1) | 1ull;
    }
    __syncthreads();   // vmcnt(0) drain here also retires the lv prefetch

    // aligned 12-float window covering [j-4, j+4]
    int basek = (j - 4) & ~3;
    if (basek < 0) basek = 0;
    if (basek > WW - 12) basek = WW - 12;
    float df0 = (float)(basek - j);

    // Phase B: per row, softmax once + 3 window searches (+never-fires fallback).
    // Pure LDS+VALU: logits already in registers.
    float Sb0 = 0.f, Sb1 = 0.f, Sb2 = 0.f, Sf0 = 0.f, Sf1 = 0.f, Sf2 = 0.f;
    float Mb0 = 0.f, Mb1 = 0.f, Mb2 = 0.f, Mf0 = 0.f, Mf1 = 0.f, Mf2 = 0.f;
#pragma unroll
    for (int rl = 0; rl < ROWS_PG; ++rl) {
        int bi = (i0 + rl) & 63;
        float l0 = lv[rl][0], l1 = lv[rl][1], l2 = lv[rl][2];
        float mx = fmaxf(l0, fmaxf(l1, l2));
        float x0 = __expf(l0 - mx), x1 = __expf(l1 - mx), x2 = __expf(l2 - mx);
        float rs = __fdividef(1.0f, x0 + x1 + x2);
        float pr0 = x0 * rs, pr1 = x1 * rs, pr2 = x2 * rs;

        float d[CC];
#pragma unroll
        for (int c = 0; c < CC; ++c) {
            const float* g2 = g2s[rl][c];
            // 3 independent b128 loads — one latency wait, no chain
            float4 W0 = *(const float4*)(g2 + basek);
            float4 W1 = *(const float4*)(g2 + basek + 4);
            float4 W2 = *(const float4*)(g2 + basek + 8);
            float df = df0;
            float mn;
            mn =           fmaf(df, df, W0.x);  df += 1.f;
            mn = fminf(mn, fmaf(df, df, W0.y)); df += 1.f;
            mn = fminf(mn, fmaf(df, df, W0.z)); df += 1.f;
            mn = fminf(mn, fmaf(df, df, W0.w)); df += 1.f;
            mn = fminf(mn, fmaf(df, df, W1.x)); df += 1.f;
            mn = fminf(mn, fmaf(df, df, W1.y)); df += 1.f;
            mn = fminf(mn, fmaf(df, df, W1.z)); df += 1.f;
            mn = fminf(mn, fmaf(df, df, W1.w)); df += 1.f;
            mn = fminf(mn, fmaf(df, df, W2.x)); df += 1.f;
            mn = fminf(mn, fmaf(df, df, W2.y)); df += 1.f;
            mn = fminf(mn, fmaf(df, df, W2.z)); df += 1.f;
            mn = fminf(mn, fmaf(df, df, W2.w));
            if (__builtin_expect(mn > 25.f, 0)) {   // radius-4 prune failed (P ~ 0)
                for (int r0 = 5; r0 < WW; r0 += CHUNK) {
                    float r0sq = (float)(r0 * r0);   // exact fp32 integer
                    if (r0sq >= mn) break;
                    float cl[CHUNK], cr[CHUNK];
#pragma unroll
                    for (int u = 0; u < CHUNK; ++u) {
                        int r = r0 + u;
                        int kl = j - r; kl = (kl < 0) ? 0 : kl;
                        int kr = j + r; kr = (kr > WW - 1) ? WW - 1 : kr;
                        cl[u] = g2[kl];
                        cr[u] = g2[kr];
                    }
#pragma unroll
                    for (int u = 0; u < CHUNK; ++u) {
                        float rr = (float)((r0 + u) * (r0 + u));
                        mn = fminf(mn, fminf(rr + cl[u], rr + cr[u]));
                    }
                }
            }
            d[c] = sqrtf(mn);
        }
        // fg_c = (t==c) ? min of other two bg dists : 0
        float f0 = ((word[0] >> bi) & 1ull) ? fminf(d[1], d[2]) : 0.f;
        float f1 = ((word[1] >> bi) & 1ull) ? fminf(d[0], d[2]) : 0.f;
        float f2 = ((word[2] >> bi) & 1ull) ? fminf(d[0], d[1]) : 0.f;

        Sb0 += pr0 * d[0]; Sb1 += pr1 * d[1]; Sb2 += pr2 * d[2];
        Sf0 += pr0 * f0;   Sf1 += pr1 * f1;   Sf2 += pr2 * f2;
        Mb0 = fmaxf(Mb0, d[0]); Mb1 = fmaxf(Mb1, d[1]); Mb2 = fmaxf(Mb2, d[2]);
        Mf0 = fmaxf(Mf0, f0);   Mf1 = fmaxf(Mf1, f1);   Mf2 = fmaxf(Mf2, f2);
    }

    // DPP wave reduction (VALU pipe) -> lane 63; then tiny cross-wave combine.
    float acc[12] = {Sb0, Sf0, Mb0, Mf0, Sb1, Sf1, Mb1, Mf1, Sb2, Sf2, Mb2, Mf2};
    int lane = j & 63, wid = j >> 6;
#pragma unroll
    for (int a = 0; a < 12; ++a) {
        bool ismax = (a & 2) != 0;         // k = a&3: 0,1 sums; 2,3 maxes
        float v = ismax ? wave_max64(acc[a]) : wave_sum64(acc[a]);
        if (lane == 63) red[a][wid] = v;
    }
    __syncthreads();
    if (j < 12) {
        int c = j >> 2, k = j & 3;
        bool ismax = (k & 2) != 0;
        float v = red[j][0];
#pragma unroll
        for (int t = 1; t < WW / 64; ++t)
            v = ismax ? fmaxf(v, red[j][t]) : (v + red[j][t]);
        out12[((size_t)(b * CC + c) * 4 + k) * GROUPS + g] = v;
    }
}

// One block: reduce 24 masks x 4 stats x 192 groups -> scalar loss.
__global__ __launch_bounds__(WW) void final_k(const float* __restrict__ out12,
                                              float* __restrict__ out) {
    __shared__ float contrib[NMASK];
    int t = threadIdx.x;
    int m = t >> 4, l = t & 15;            // 24 masks x 16 lanes
    const float* pm = out12 + (size_t)m * 4 * GROUPS;
    // batch all loads: one stall group instead of chained waits
    float t0[12], t1[12], t2[12], t3[12];
#pragma unroll
    for (int q = 0; q < 12; ++q) {
        int gg = q * 16 + l;
        t0[q] = pm[0 * GROUPS + gg];
        t1[q] = pm[1 * GROUPS + gg];
        t2[q] = pm[2 * GROUPS + gg];
        t3[q] = pm[3 * GROUPS + gg];
    }
    float sb = 0.f, sf = 0.f, mb = 0.f, mf = 0.f;
#pragma unroll
    for (int q = 0; q < 12; ++q) {
        sb += t0[q]; sf += t1[q];
        mb = fmaxf(mb, t2[q]); mf = fmaxf(mf, t3[q]);
    }
#pragma unroll
    for (int off = 8; off > 0; off >>= 1) {
        sb += __shfl_down(sb, off, 16);
        sf += __shfl_down(sf, off, 16);
        mb = fmaxf(mb, __shfl_down(mb, off, 16));
        mf = fmaxf(mf, __shfl_down(mf, off, 16));
    }
    if (l == 0) {
        float cv = 0.f;
        if (mb <= 1000.0f)                 // mask non-empty
            cv = sb / fmaxf(mb, 1e-12f) - sf / fmaxf(mf, 1e-12f);
        contrib[m] = cv;
    }
    __syncthreads();
    if (t == 0) {
        float tot = 0.f;
        for (int mk = 0; mk < NMASK; ++mk) tot += contrib[mk];
        out[0] = tot / (float)((size_t)BB * CC * PLANE);
    }
}

extern "C" void kernel_launch(void* const* d_in, const int* in_sizes, int n_in,
                              void* d_out, int out_size, void* d_ws, size_t ws_size,
                              hipStream_t stream) {
    const float* logits = (const float*)d_in[0];   // [8,3,384,384] f32
    const int* targets = (const int*)d_in[1];      // [8,384,384] i32
    float* out = (float*)d_out;                    // scalar f32

    u64* bm = (u64*)d_ws;                                       // 55296 u64
    float* out12 = (float*)(bm + (size_t)BB * CC * NW * WW);    // 18432 floats

    {
        dim3 grid(BB, NW, 4);                                   // 192 blocks
        buildbm<<<grid, WW, 0, stream>>>(targets, (u16*)bm);
    }
    {
        dim3 grid(GROUPS, BB);                                  // 192*8 = 1536 blocks
        edt4w<<<grid, WW, 0, stream>>>(bm, logits, out12);
    }
    final_k<<<1, WW, 0, stream>>>(out12, out);
}

// Round 6
// 79.649 us; speedup vs baseline: 1.0461x; 1.0272x over previous
//
#include <hip/hip_runtime.h>

typedef unsigned long long u64;
typedef unsigned short u16;

#define HH 384
#define WW 384
#define BB 8
#define CC 3
#define NMASK (BB*CC)        // 24
#define PLANE (HH*WW)        // 147456
#define NW 6                 // 384 rows = 6 x 64-bit words
#define ROWS_PG 4            // 4 | 64 -> a row group never spans bitmask words
#define GROUPS 96            // 384/4 -> 768 blocks = 3.0/CU exact
#define CHUNK 4              // fallback ring radii per batch
#define AUXW 8               // padded u16 slots per (b,c,j): one 16B vector
#define INF_F 1.0e6f

// ---------------------------------------------------------------------------
// Algebra: only the 3 per-class bg EDT fields d_c(q)=dist(q,{t==c}) are
// computed. fg_c(q)=dist(q,{t!=c}) = 0 where t(q)!=c, else min of the other
// two d's (dist-to-union = min of dists; bit-exact, sqrt monotone).
// loss = sum_m S_bg/max_bg - S_fg/max_fg  (divide-after-sum; ~1e-7 rel)
// mask non-empty <=> max_bg <= 1000 (real EDT max < 542; empty-set >= 1e6)
//
// Cross-round ledger (total incl. ~42us harness poison fill):
//  r0 ROWS_PG=4 768blk 3-kernel:        80.4
//  r1 fused+fences:                     99.8  (buffer_wbl2 storm)
//  r2 fused relaxed, ROWS_PG=2:         90.0  (agent-RMW backlog)
//  r3 3-kernel + batched loads:         79.0  (best)
//  r4 ROWS_PG=8 384blk:                 83.3  (1.5 blk/CU imbalance)
//  r5 ROWS_PG=2 1536blk 3-kernel:       81.8  (front duplicated x2: TLP
//     gain < front cost -> shape levers exhausted, ROWS_PG=4/768 optimal)
//
// Round-6 change (front redundancy + occupancy class):
//  * buildbm now grid (8,6): each block owns one full 64-row word, writes
//    the u64 word AND a u16 seed summary (last<<8|first, 0xFFFF if empty)
//    per (c,j), padded to 8 u16 = one aligned uint4 per (b,c,j).
//  * edt4w front: 3 word loads + 3 uint4 aux loads + 12 logits = 18 load
//    instrs (was 30) and NO 6-word u64 clz/ctz scans — P/N from six u16
//    compares (bit-identical values). The 36-VGPR wb[][] array is gone ->
//    fits __launch_bounds__(384,8) (VGPR cap 64) -> 8-wave/SIMD occupancy
//    class -> full 3 blocks/CU resident (r3's ~96 VGPR likely capped
//    residency at 2 blocks/CU per the 64/128 VGPR halving model).
//
// ws layout:
//   u64   bm[BB][CC][NW][WW]         column word bitmasks   (442368 B)
//   u16   aux[BB][CC][WW][AUXW]      per-word seed summary  (147456 B)
//   float out12[NMASK][4][GROUPS]    per-(b,c) partials
// ---------------------------------------------------------------------------

template <int CTRL>
__device__ __forceinline__ float dpp_mov(float v) {
    return __int_as_float(__builtin_amdgcn_update_dpp(
        0, __float_as_int(v), CTRL, 0xf, 0xf, true));
}
__device__ __forceinline__ float wave_sum64(float v) {
    v += dpp_mov<0x111>(v);   // row_shr:1
    v += dpp_mov<0x112>(v);   // row_shr:2
    v += dpp_mov<0x114>(v);   // row_shr:4
    v += dpp_mov<0x118>(v);   // row_shr:8  -> lane15 of each row = row sum
    v += dpp_mov<0x142>(v);   // row_bcast:15
    v += dpp_mov<0x143>(v);   // row_bcast:31 -> lane63 = total
    return v;                 // valid in lane 63 (identity 0 shifts in zeros)
}
__device__ __forceinline__ float wave_max64(float v) {
    v = fmaxf(v, dpp_mov<0x111>(v));
    v = fmaxf(v, dpp_mov<0x112>(v));
    v = fmaxf(v, dpp_mov<0x114>(v));
    v = fmaxf(v, dpp_mov<0x118>(v));
    v = fmaxf(v, dpp_mov<0x142>(v));
    v = fmaxf(v, dpp_mov<0x143>(v));
    return v;                 // valid in lane 63 (identity 0: inputs >= 0)
}

// Grid (BB, NW), 384 threads: thread j owns column j of word w — reads all
// 64 rows (batched), emits 3 class words + 3 packed seed summaries.
__global__ __launch_bounds__(WW, 4) void buildbm(const int* __restrict__ targets,
                                                 u64* __restrict__ bm,
                                                 u16* __restrict__ aux) {
    int b = blockIdx.x, w = blockIdx.y;
    int j = threadIdx.x;
    const int* tg = targets + (size_t)b * PLANE + (w * 64) * WW + j;
    int t[64];
#pragma unroll
    for (int r = 0; r < 64; ++r) t[r] = tg[r * WW];   // one batched stall group
    u64 m0 = 0, m1 = 0, m2 = 0;
#pragma unroll
    for (int r = 0; r < 64; ++r) {
        u64 bit = 1ull << r;
        m0 |= (t[r] == 0) ? bit : 0ull;
        m1 |= (t[r] == 1) ? bit : 0ull;
        m2 |= (t[r] == 2) ? bit : 0ull;
    }
    size_t base = (((size_t)b * CC) * NW + w) * WW + j;          // c = 0
    bm[base] = m0;
    bm[base + (size_t)NW * WW] = m1;
    bm[base + 2 * (size_t)NW * WW] = m2;
    u16 a0 = m0 ? (u16)(((63 - __builtin_clzll(m0)) << 8) | __builtin_ctzll(m0)) : (u16)0xFFFF;
    u16 a1 = m1 ? (u16)(((63 - __builtin_clzll(m1)) << 8) | __builtin_ctzll(m1)) : (u16)0xFFFF;
    u16 a2 = m2 ? (u16)(((63 - __builtin_clzll(m2)) << 8) | __builtin_ctzll(m2)) : (u16)0xFFFF;
    size_t abase = (((size_t)b * CC) * WW + j) * AUXW + w;       // c = 0
    aux[abase] = a0;
    aux[abase + (size_t)WW * AUXW] = a1;
    aux[abase + 2 * (size_t)WW * AUXW] = a2;
}

// Grid (GROUPS, BB): block = 4 rows x 384 cols, all 3 classes.
__global__ __launch_bounds__(WW, 8) void edt4w(const u64* __restrict__ bm,
                                               const u16* __restrict__ aux,
                                               const float* __restrict__ logits,
                                               float* __restrict__ out12) {
    __shared__ __align__(16) float g2s[ROWS_PG][CC][WW];   // 18432 B
    __shared__ float red[12][WW / 64];
    int g = blockIdx.x, b = blockIdx.y;
    int j = threadIdx.x;
    int i0 = g * ROWS_PG;
    int w = i0 >> 6;
    int wbase = w << 6;

    // ---- batched front: 3 u64 + 3 uint4 + 12 f32 = 18 load instrs ----
    u64 word[CC];
#pragma unroll
    for (int c = 0; c < CC; ++c)
        word[c] = bm[(((size_t)b * CC + c) * NW + w) * WW + j];
    uint4 ax[CC];
#pragma unroll
    for (int c = 0; c < CC; ++c)
        ax[c] = *(const uint4*)(aux + (((size_t)b * CC + c) * WW + j) * AUXW);
    const float* lg = logits + ((size_t)b * CC * HH + i0) * WW + j;
    float lv[ROWS_PG][CC];
#pragma unroll
    for (int rl = 0; rl < ROWS_PG; ++rl) {
        lv[rl][0] = lg[rl * WW];
        lv[rl][1] = lg[PLANE + rl * WW];
        lv[rl][2] = lg[2 * PLANE + rl * WW];
    }

    // P/N from seed summaries (bit-identical to the old 6-word clz/ctz scan)
    int P[CC], N[CC];
#pragma unroll
    for (int c = 0; c < CC; ++c) {
        unsigned e0 = ax[c].x & 0xFFFFu, e1 = ax[c].x >> 16;
        unsigned e2 = ax[c].y & 0xFFFFu, e3 = ax[c].y >> 16;
        unsigned e4 = ax[c].z & 0xFFFFu, e5 = ax[c].z >> 16;
        unsigned e[NW] = {e0, e1, e2, e3, e4, e5};
        int p = -1, n = -1;
#pragma unroll
        for (int wq = 0; wq < NW; ++wq)
            if (wq < w && e[wq] != 0xFFFFu) p = wq * 64 + (int)(e[wq] >> 8);
#pragma unroll
        for (int wq = NW - 1; wq >= 0; --wq)
            if (wq > w && e[wq] != 0xFFFFu) n = wq * 64 + (int)(e[wq] & 0xFFu);
        P[c] = p; N[c] = n;
    }

    // Phase A: 4 rows x 3 classes of exact column distances -> LDS.
    u64 lowmask = ((1ull << (i0 & 63)) << 1) - 1ull;    // bits 0..bi
#pragma unroll
    for (int rl = 0; rl < ROWS_PG; ++rl) {
        int i = i0 + rl;
        u64 himask = ~(lowmask >> 1);                   // bits bi..63
#pragma unroll
        for (int c = 0; c < CC; ++c) {
            u64 lo = word[c] & lowmask;
            int last = lo ? (wbase + 63 - __builtin_clzll(lo | 1ull)) : P[c];
            u64 hi = word[c] & himask;
            int next = hi ? (wbase + (int)__builtin_ctzll(hi | 0x8000000000000000ull)) : N[c];
            float fwd = (last >= 0) ? (float)(i - last) : (INF_F + (float)(i + 1));
            float bwd = (next >= 0) ? (float)(next - i) : (INF_F + (float)(HH - i));
            float gc = fminf(fwd, bwd);
            g2s[rl][c][j] = gc * gc;
        }
        lowmask = (lowmask << 1) | 1ull;
    }
    __syncthreads();   // vmcnt(0) drain here also retires the lv prefetch

    // aligned 12-float window covering [j-4, j+4]
    int basek = (j - 4) & ~3;
    if (basek < 0) basek = 0;
    if (basek > WW - 12) basek = WW - 12;
    float df0 = (float)(basek - j);

    // Phase B: per row, softmax once + 3 window searches (+never-fires fallback).
    // Pure LDS+VALU: logits already in registers.
    float Sb0 = 0.f, Sb1 = 0.f, Sb2 = 0.f, Sf0 = 0.f, Sf1 = 0.f, Sf2 = 0.f;
    float Mb0 = 0.f, Mb1 = 0.f, Mb2 = 0.f, Mf0 = 0.f, Mf1 = 0.f, Mf2 = 0.f;
#pragma unroll
    for (int rl = 0; rl < ROWS_PG; ++rl) {
        int bi = (i0 + rl) & 63;
        float l0 = lv[rl][0], l1 = lv[rl][1], l2 = lv[rl][2];
        float mx = fmaxf(l0, fmaxf(l1, l2));
        float x0 = __expf(l0 - mx), x1 = __expf(l1 - mx), x2 = __expf(l2 - mx);
        float rs = __fdividef(1.0f, x0 + x1 + x2);
        float pr0 = x0 * rs, pr1 = x1 * rs, pr2 = x2 * rs;

        float d[CC];
#pragma unroll
        for (int c = 0; c < CC; ++c) {
            const float* g2 = g2s[rl][c];
            // 3 independent b128 loads — one latency wait, no chain
            float4 W0 = *(const float4*)(g2 + basek);
            float4 W1 = *(const float4*)(g2 + basek + 4);
            float4 W2 = *(const float4*)(g2 + basek + 8);
            float df = df0;
            float mn;
            mn =           fmaf(df, df, W0.x);  df += 1.f;
            mn = fminf(mn, fmaf(df, df, W0.y)); df += 1.f;
            mn = fminf(mn, fmaf(df, df, W0.z)); df += 1.f;
            mn = fminf(mn, fmaf(df, df, W0.w)); df += 1.f;
            mn = fminf(mn, fmaf(df, df, W1.x)); df += 1.f;
            mn = fminf(mn, fmaf(df, df, W1.y)); df += 1.f;
            mn = fminf(mn, fmaf(df, df, W1.z)); df += 1.f;
            mn = fminf(mn, fmaf(df, df, W1.w)); df += 1.f;
            mn = fminf(mn, fmaf(df, df, W2.x)); df += 1.f;
            mn = fminf(mn, fmaf(df, df, W2.y)); df += 1.f;
            mn = fminf(mn, fmaf(df, df, W2.z)); df += 1.f;
            mn = fminf(mn, fmaf(df, df, W2.w));
            if (__builtin_expect(mn > 25.f, 0)) {   // radius-4 prune failed (P ~ 0)
                for (int r0 = 5; r0 < WW; r0 += CHUNK) {
                    float r0sq = (float)(r0 * r0);   // exact fp32 integer
                    if (r0sq >= mn) break;
                    float cl[CHUNK], cr[CHUNK];
#pragma unroll
                    for (int u = 0; u < CHUNK; ++u) {
                        int r = r0 + u;
                        int kl = j - r; kl = (kl < 0) ? 0 : kl;
                        int kr = j + r; kr = (kr > WW - 1) ? WW - 1 : kr;
                        cl[u] = g2[kl];
                        cr[u] = g2[kr];
                    }
#pragma unroll
                    for (int u = 0; u < CHUNK; ++u) {
                        float rr = (float)((r0 + u) * (r0 + u));
                        mn = fminf(mn, fminf(rr + cl[u], rr + cr[u]));
                    }
                }
            }
            d[c] = sqrtf(mn);
        }
        // fg_c = (t==c) ? min of other two bg dists : 0
        float f0 = ((word[0] >> bi) & 1ull) ? fminf(d[1], d[2]) : 0.f;
        float f1 = ((word[1] >> bi) & 1ull) ? fminf(d[0], d[2]) : 0.f;
        float f2 = ((word[2] >> bi) & 1ull) ? fminf(d[0], d[1]) : 0.f;

        Sb0 += pr0 * d[0]; Sb1 += pr1 * d[1]; Sb2 += pr2 * d[2];
        Sf0 += pr0 * f0;   Sf1 += pr1 * f1;   Sf2 += pr2 * f2;
        Mb0 = fmaxf(Mb0, d[0]); Mb1 = fmaxf(Mb1, d[1]); Mb2 = fmaxf(Mb2, d[2]);
        Mf0 = fmaxf(Mf0, f0);   Mf1 = fmaxf(Mf1, f1);   Mf2 = fmaxf(Mf2, f2);
    }

    // DPP wave reduction (VALU pipe) -> lane 63; then tiny cross-wave combine.
    float acc[12] = {Sb0, Sf0, Mb0, Mf0, Sb1, Sf1, Mb1, Mf1, Sb2, Sf2, Mb2, Mf2};
    int lane = j & 63, wid = j >> 6;
#pragma unroll
    for (int a = 0; a < 12; ++a) {
        bool ismax = (a & 2) != 0;         // k = a&3: 0,1 sums; 2,3 maxes
        float v = ismax ? wave_max64(acc[a]) : wave_sum64(acc[a]);
        if (lane == 63) red[a][wid] = v;
    }
    __syncthreads();
    if (j < 12) {
        int c = j >> 2, k = j & 3;
        bool ismax = (k & 2) != 0;
        float v = red[j][0];
#pragma unroll
        for (int t = 1; t < WW / 64; ++t)
            v = ismax ? fmaxf(v, red[j][t]) : (v + red[j][t]);
        out12[((size_t)(b * CC + c) * 4 + k) * GROUPS + g] = v;
    }
}

// One block: reduce 24 masks x 4 stats x 96 groups -> scalar loss.
__global__ __launch_bounds__(WW) void final_k(const float* __restrict__ out12,
                                              float* __restrict__ out) {
    __shared__ float contrib[NMASK];
    int t = threadIdx.x;
    int m = t >> 4, l = t & 15;            // 24 masks x 16 lanes
    const float* pm = out12 + (size_t)m * 4 * GROUPS;
    // batch all 24 loads: one stall group instead of 6 chained waits
    float t0[6], t1[6], t2[6], t3[6];
#pragma unroll
    for (int q = 0; q < 6; ++q) {
        int gg = q * 16 + l;
        t0[q] = pm[0 * GROUPS + gg];
        t1[q] = pm[1 * GROUPS + gg];
        t2[q] = pm[2 * GROUPS + gg];
        t3[q] = pm[3 * GROUPS + gg];
    }
    float sb = 0.f, sf = 0.f, mb = 0.f, mf = 0.f;
#pragma unroll
    for (int q = 0; q < 6; ++q) {
        sb += t0[q]; sf += t1[q];
        mb = fmaxf(mb, t2[q]); mf = fmaxf(mf, t3[q]);
    }
#pragma unroll
    for (int off = 8; off > 0; off >>= 1) {
        sb += __shfl_down(sb, off, 16);
        sf += __shfl_down(sf, off, 16);
        mb = fmaxf(mb, __shfl_down(mb, off, 16));
        mf = fmaxf(mf, __shfl_down(mf, off, 16));
    }
    if (l == 0) {
        float cv = 0.f;
        if (mb <= 1000.0f)                 // mask non-empty
            cv = sb / fmaxf(mb, 1e-12f) - sf / fmaxf(mf, 1e-12f);
        contrib[m] = cv;
    }
    __syncthreads();
    if (t == 0) {
        float tot = 0.f;
        for (int mk = 0; mk < NMASK; ++mk) tot += contrib[mk];
        out[0] = tot / (float)((size_t)BB * CC * PLANE);
    }
}

extern "C" void kernel_launch(void* const* d_in, const int* in_sizes, int n_in,
                              void* d_out, int out_size, void* d_ws, size_t ws_size,
                              hipStream_t stream) {
    const float* logits = (const float*)d_in[0];   // [8,3,384,384] f32
    const int* targets = (const int*)d_in[1];      // [8,384,384] i32
    float* out = (float*)d_out;                    // scalar f32

    u64* bm = (u64*)d_ws;                                       // 442368 B
    u16* aux = (u16*)(bm + (size_t)BB * CC * NW * WW);          // 147456 B
    float* out12 = (float*)(aux + (size_t)BB * CC * WW * AUXW); // 9216 floats

    {
        dim3 grid(BB, NW);                                      // 48 blocks
        buildbm<<<grid, WW, 0, stream>>>(targets, bm, aux);
    }
    {
        dim3 grid(GROUPS, BB);                                  // 96*8 = 768 blocks
        edt4w<<<grid, WW, 0, stream>>>(bm, aux, logits, out12);
    }
    final_k<<<1, WW, 0, stream>>>(out12, out);
}

// Round 7
// 79.366 us; speedup vs baseline: 1.0499x; 1.0036x over previous
//
#include <hip/hip_runtime.h>

typedef unsigned long long u64;
typedef unsigned short u16;

#define HH 384
#define WW 384
#define BB 8
#define CC 3
#define NMASK (BB*CC)        // 24
#define PLANE (HH*WW)        // 147456
#define NW 6                 // 384 rows = 6 x 64-bit words
#define ROWS_PG 4            // 4 | 64 -> a row group never spans bitmask words
#define GROUPS 96            // 384/4 -> 768 blocks = 3/CU even
#define CHUNK 4              // fallback ring radii per batch
#define INF_F 1.0e6f

// ---------------------------------------------------------------------------
// Algebra: only the 3 per-class bg EDT fields d_c(q)=dist(q,{t==c}) are
// computed. fg_c(q)=dist(q,{t!=c}) = 0 where t(q)!=c, else min of the other
// two d's (dist-to-union = min of dists; bit-exact, sqrt monotone).
// loss = sum_m S_bg/max_bg - S_fg/max_fg  (divide-after-sum; ~1e-7 rel)
// mask non-empty <=> max_bg <= 1000 (real EDT max < 542; empty-set >= 1e6)
//
// FINAL STRUCTURE (revert to r3, best measured 79.0):
// 3 kernels, stream-ordered coherence. Cross-round ledger (noise +-1.5us;
// total includes ~42us harness poison-fill at 80% HBM peak, uncontrollable):
//  r0 ROWS_PG=4 768blk 3-kernel:        80.4
//  r1 fused+fences:                     99.8  (buffer_wbl2 storm per block)
//  r2 fused relaxed, ROWS_PG=2:         90.0  (same-address agent-RMW backlog)
//  r3 3-kernel + batched loads:         79.0  (BEST - this kernel)
//  r4 ROWS_PG=8 384blk:                 83.3  (1.5 blk/CU imbalance)
//  r5 ROWS_PG=2 1536blk 3-kernel:       81.8  (front duplicated x2)
//  r6 aux-table front + VGPR<64:        79.6  (neutral - front not the cost)
// Conclusions locked in: fusion loses on gfx950 coherence costs; grid shape
// optimum is ROWS_PG=4/768blk; batched single-stall-group loads help; the
// residual chain time is latency/launch floor, not throughput.
//
// ws layout:
//   u64   bm[BB][CC][NW][WW]        column seed bitmasks (442368 B)
//   float out12[NMASK][4][GROUPS]   per-(b,c): {Sbg,Sfg,Mbg,Mfg} x rowgroup
// ---------------------------------------------------------------------------

template <int CTRL>
__device__ __forceinline__ float dpp_mov(float v) {
    return __int_as_float(__builtin_amdgcn_update_dpp(
        0, __float_as_int(v), CTRL, 0xf, 0xf, true));
}
__device__ __forceinline__ float wave_sum64(float v) {
    v += dpp_mov<0x111>(v);   // row_shr:1
    v += dpp_mov<0x112>(v);   // row_shr:2
    v += dpp_mov<0x114>(v);   // row_shr:4
    v += dpp_mov<0x118>(v);   // row_shr:8  -> lane15 of each row = row sum
    v += dpp_mov<0x142>(v);   // row_bcast:15
    v += dpp_mov<0x143>(v);   // row_bcast:31 -> lane63 = total
    return v;                 // valid in lane 63 (identity 0 shifts in zeros)
}
__device__ __forceinline__ float wave_max64(float v) {
    v = fmaxf(v, dpp_mov<0x111>(v));
    v = fmaxf(v, dpp_mov<0x112>(v));
    v = fmaxf(v, dpp_mov<0x114>(v));
    v = fmaxf(v, dpp_mov<0x118>(v));
    v = fmaxf(v, dpp_mov<0x142>(v));
    v = fmaxf(v, dpp_mov<0x143>(v));
    return v;                 // valid in lane 63 (identity 0: inputs >= 0)
}

// Grid (BB, NW, 4): thread j builds a 16-bit partial of the 64-row bitmask
// word for its column, all 3 classes (u16 stores, little-endian, no atomics).
__global__ __launch_bounds__(WW) void buildbm(const int* __restrict__ targets,
                                              u16* __restrict__ bm16) {
    int b = blockIdx.x, w = blockIdx.y, q = blockIdx.z;
    int j = threadIdx.x;
    const int* tg = targets + (size_t)b * PLANE + (w * 64 + q * 16) * WW + j;
    int t[16];
#pragma unroll
    for (int r = 0; r < 16; ++r) t[r] = tg[r * WW];   // batch: one stall group
    unsigned m0 = 0, m1 = 0, m2 = 0;
#pragma unroll
    for (int r = 0; r < 16; ++r) {
        unsigned bit = 1u << r;
        m0 |= (t[r] == 0) ? bit : 0u;
        m1 |= (t[r] == 1) ? bit : 0u;
        m2 |= (t[r] == 2) ? bit : 0u;
    }
    size_t base = (((size_t)b * CC) * NW + w) * WW + j;          // c = 0
    bm16[base * 4 + q] = (u16)m0;
    bm16[(base + (size_t)NW * WW) * 4 + q] = (u16)m1;
    bm16[(base + 2 * (size_t)NW * WW) * 4 + q] = (u16)m2;
}

// Grid (GROUPS, BB): block = 4 rows x 384 cols, all 3 classes.
__global__ __launch_bounds__(WW, 5) void edt4w(const u64* __restrict__ bm,
                                               const float* __restrict__ logits,
                                               float* __restrict__ out12) {
    __shared__ __align__(16) float g2s[ROWS_PG][CC][WW];   // 18432 B
    __shared__ float red[12][WW / 64];
    int g = blockIdx.x, b = blockIdx.y;
    int j = threadIdx.x;
    int i0 = g * ROWS_PG;
    int w = i0 >> 6;
    int wbase = w << 6;

    // ---- batch-issue ALL global loads: one stall group per wave ----
    u64 wb[CC][NW];
#pragma unroll
    for (int c = 0; c < CC; ++c)
#pragma unroll
        for (int wq = 0; wq < NW; ++wq)
            wb[c][wq] = bm[(((size_t)b * CC + c) * NW + wq) * WW + j];

    const float* lg = logits + ((size_t)b * CC * HH + i0) * WW + j;
    float lv[ROWS_PG][CC];
#pragma unroll
    for (int rl = 0; rl < ROWS_PG; ++rl) {
        lv[rl][0] = lg[rl * WW];
        lv[rl][1] = lg[PLANE + rl * WW];
        lv[rl][2] = lg[2 * PLANE + rl * WW];
    }

    u64 word[CC];
    int P[CC], N[CC];
#pragma unroll
    for (int c = 0; c < CC; ++c) {
        int p = -1, n = -1;
#pragma unroll
        for (int wq = 0; wq < NW; ++wq)
            if (wq < w && wb[c][wq]) p = wq * 64 + 63 - __builtin_clzll(wb[c][wq] | 1ull);
#pragma unroll
        for (int wq = NW - 1; wq >= 0; --wq)
            if (wq > w && wb[c][wq]) n = wq * 64 + (int)__builtin_ctzll(wb[c][wq] | 0x8000000000000000ull);
        P[c] = p; N[c] = n;
        // dynamic-uniform index w: select chain, not scratch (rule #20)
        u64 wd = wb[c][0];
#pragma unroll
        for (int wq = 1; wq < NW; ++wq) wd = (w == wq) ? wb[c][wq] : wd;
        word[c] = wd;
    }

    // Phase A: 4 rows x 3 classes of exact column distances -> LDS.
    u64 lowmask = ((1ull << (i0 & 63)) << 1) - 1ull;    // bits 0..bi
#pragma unroll
    for (int rl = 0; rl < ROWS_PG; ++rl) {
        int i = i0 + rl;
        u64 himask = ~(lowmask >> 1);                   // bits bi..63
#pragma unroll
        for (int c = 0; c < CC; ++c) {
            u64 lo = word[c] & lowmask;
            int last = lo ? (wbase + 63 - __builtin_clzll(lo | 1ull)) : P[c];
            u64 hi = word[c] & himask;
            int next = hi ? (wbase + (int)__builtin_ctzll(hi | 0x8000000000000000ull)) : N[c];
            float fwd = (last >= 0) ? (float)(i - last) : (INF_F + (float)(i + 1));
            float bwd = (next >= 0) ? (float)(next - i) : (INF_F + (float)(HH - i));
            float gc = fminf(fwd, bwd);
            g2s[rl][c][j] = gc * gc;
        }
        lowmask = (lowmask << 1) | 1ull;
    }
    __syncthreads();   // vmcnt(0) drain here also retires the lv prefetch

    // aligned 12-float window covering [j-4, j+4]
    int basek = (j - 4) & ~3;
    if (basek < 0) basek = 0;
    if (basek > WW - 12) basek = WW - 12;
    float df0 = (float)(basek - j);

    // Phase B: per row, softmax once + 3 window searches (+never-fires fallback).
    // Pure LDS+VALU: logits already in registers.
    float Sb0 = 0.f, Sb1 = 0.f, Sb2 = 0.f, Sf0 = 0.f, Sf1 = 0.f, Sf2 = 0.f;
    float Mb0 = 0.f, Mb1 = 0.f, Mb2 = 0.f, Mf0 = 0.f, Mf1 = 0.f, Mf2 = 0.f;
#pragma unroll
    for (int rl = 0; rl < ROWS_PG; ++rl) {
        int bi = (i0 + rl) & 63;
        float l0 = lv[rl][0], l1 = lv[rl][1], l2 = lv[rl][2];
        float mx = fmaxf(l0, fmaxf(l1, l2));
        float x0 = __expf(l0 - mx), x1 = __expf(l1 - mx), x2 = __expf(l2 - mx);
        float rs = __fdividef(1.0f, x0 + x1 + x2);
        float pr0 = x0 * rs, pr1 = x1 * rs, pr2 = x2 * rs;

        float d[CC];
#pragma unroll
        for (int c = 0; c < CC; ++c) {
            const float* g2 = g2s[rl][c];
            // 3 independent b128 loads — one latency wait, no chain
            float4 W0 = *(const float4*)(g2 + basek);
            float4 W1 = *(const float4*)(g2 + basek + 4);
            float4 W2 = *(const float4*)(g2 + basek + 8);
            float df = df0;
            float mn;
            mn =           fmaf(df, df, W0.x);  df += 1.f;
            mn = fminf(mn, fmaf(df, df, W0.y)); df += 1.f;
            mn = fminf(mn, fmaf(df, df, W0.z)); df += 1.f;
            mn = fminf(mn, fmaf(df, df, W0.w)); df += 1.f;
            mn = fminf(mn, fmaf(df, df, W1.x)); df += 1.f;
            mn = fminf(mn, fmaf(df, df, W1.y)); df += 1.f;
            mn = fminf(mn, fmaf(df, df, W1.z)); df += 1.f;
            mn = fminf(mn, fmaf(df, df, W1.w)); df += 1.f;
            mn = fminf(mn, fmaf(df, df, W2.x)); df += 1.f;
            mn = fminf(mn, fmaf(df, df, W2.y)); df += 1.f;
            mn = fminf(mn, fmaf(df, df, W2.z)); df += 1.f;
            mn = fminf(mn, fmaf(df, df, W2.w));
            if (__builtin_expect(mn > 25.f, 0)) {   // radius-4 prune failed (P ~ 0)
                for (int r0 = 5; r0 < WW; r0 += CHUNK) {
                    float r0sq = (float)(r0 * r0);   // exact fp32 integer
                    if (r0sq >= mn) break;
                    float cl[CHUNK], cr[CHUNK];
#pragma unroll
                    for (int u = 0; u < CHUNK; ++u) {
                        int r = r0 + u;
                        int kl = j - r; kl = (kl < 0) ? 0 : kl;
                        int kr = j + r; kr = (kr > WW - 1) ? WW - 1 : kr;
                        cl[u] = g2[kl];
                        cr[u] = g2[kr];
                    }
#pragma unroll
                    for (int u = 0; u < CHUNK; ++u) {
                        float rr = (float)((r0 + u) * (r0 + u));
                        mn = fminf(mn, fminf(rr + cl[u], rr + cr[u]));
                    }
                }
            }
            d[c] = sqrtf(mn);
        }
        // fg_c = (t==c) ? min of other two bg dists : 0
        float f0 = ((word[0] >> bi) & 1ull) ? fminf(d[1], d[2]) : 0.f;
        float f1 = ((word[1] >> bi) & 1ull) ? fminf(d[0], d[2]) : 0.f;
        float f2 = ((word[2] >> bi) & 1ull) ? fminf(d[0], d[1]) : 0.f;

        Sb0 += pr0 * d[0]; Sb1 += pr1 * d[1]; Sb2 += pr2 * d[2];
        Sf0 += pr0 * f0;   Sf1 += pr1 * f1;   Sf2 += pr2 * f2;
        Mb0 = fmaxf(Mb0, d[0]); Mb1 = fmaxf(Mb1, d[1]); Mb2 = fmaxf(Mb2, d[2]);
        Mf0 = fmaxf(Mf0, f0);   Mf1 = fmaxf(Mf1, f1);   Mf2 = fmaxf(Mf2, f2);
    }

    // DPP wave reduction (VALU pipe) -> lane 63; then tiny cross-wave combine.
    float acc[12] = {Sb0, Sf0, Mb0, Mf0, Sb1, Sf1, Mb1, Mf1, Sb2, Sf2, Mb2, Mf2};
    int lane = j & 63, wid = j >> 6;
#pragma unroll
    for (int a = 0; a < 12; ++a) {
        bool ismax = (a & 2) != 0;         // k = a&3: 0,1 sums; 2,3 maxes
        float v = ismax ? wave_max64(acc[a]) : wave_sum64(acc[a]);
        if (lane == 63) red[a][wid] = v;
    }
    __syncthreads();
    if (j < 12) {
        int c = j >> 2, k = j & 3;
        bool ismax = (k & 2) != 0;
        float v = red[j][0];
#pragma unroll
        for (int t = 1; t < WW / 64; ++t)
            v = ismax ? fmaxf(v, red[j][t]) : (v + red[j][t]);
        out12[((size_t)(b * CC + c) * 4 + k) * GROUPS + g] = v;
    }
}

// One block: reduce 24 masks x 4 stats x 96 groups -> scalar loss.
__global__ __launch_bounds__(WW) void final_k(const float* __restrict__ out12,
                                              float* __restrict__ out) {
    __shared__ float contrib[NMASK];
    int t = threadIdx.x;
    int m = t >> 4, l = t & 15;            // 24 masks x 16 lanes
    const float* pm = out12 + (size_t)m * 4 * GROUPS;
    // batch all 24 loads: one stall group instead of 6 chained waits
    float t0[6], t1[6], t2[6], t3[6];
#pragma unroll
    for (int q = 0; q < 6; ++q) {
        int gg = q * 16 + l;
        t0[q] = pm[0 * GROUPS + gg];
        t1[q] = pm[1 * GROUPS + gg];
        t2[q] = pm[2 * GROUPS + gg];
        t3[q] = pm[3 * GROUPS + gg];
    }
    float sb = 0.f, sf = 0.f, mb = 0.f, mf = 0.f;
#pragma unroll
    for (int q = 0; q < 6; ++q) {
        sb += t0[q]; sf += t1[q];
        mb = fmaxf(mb, t2[q]); mf = fmaxf(mf, t3[q]);
    }
#pragma unroll
    for (int off = 8; off > 0; off >>= 1) {
        sb += __shfl_down(sb, off, 16);
        sf += __shfl_down(sf, off, 16);
        mb = fmaxf(mb, __shfl_down(mb, off, 16));
        mf = fmaxf(mf, __shfl_down(mf, off, 16));
    }
    if (l == 0) {
        float cv = 0.f;
        if (mb <= 1000.0f)                 // mask non-empty
            cv = sb / fmaxf(mb, 1e-12f) - sf / fmaxf(mf, 1e-12f);
        contrib[m] = cv;
    }
    __syncthreads();
    if (t == 0) {
        float tot = 0.f;
        for (int mk = 0; mk < NMASK; ++mk) tot += contrib[mk];
        out[0] = tot / (float)((size_t)BB * CC * PLANE);
    }
}

extern "C" void kernel_launch(void* const* d_in, const int* in_sizes, int n_in,
                              void* d_out, int out_size, void* d_ws, size_t ws_size,
                              hipStream_t stream) {
    const float* logits = (const float*)d_in[0];   // [8,3,384,384] f32
    const int* targets = (const int*)d_in[1];      // [8,384,384] i32
    float* out = (float*)d_out;                    // scalar f32

    u64* bm = (u64*)d_ws;                                       // 55296 u64
    float* out12 = (float*)(bm + (size_t)BB * CC * NW * WW);    // 9216 floats

    {
        dim3 grid(BB, NW, 4);                                   // 192 blocks
        buildbm<<<grid, WW, 0, stream>>>(targets, (u16*)bm);
    }
    {
        dim3 grid(GROUPS, BB);                                  // 96*8 = 768 blocks
        edt4w<<<grid, WW, 0, stream>>>(bm, logits, out12);
    }
    final_k<<<1, WW, 0, stream>>>(out12, out);
}